// Round 4
// baseline (375.420 us; speedup 1.0000x reference)
//
#include <hip/hip_runtime.h>
#include <stdint.h>

// Problem: B=32, T=128, C=64, DIN=DOUT=32, 4 gates.
#define T_STEPS 128
#define C_CH    64
#define HS      40   // h-plane row stride in shorts (80 B = 5x16B: aligned, bank-spread)

using frag_ab = __attribute__((ext_vector_type(8))) short;  // 8 bf16
using frag_cd = __attribute__((ext_vector_type(4))) float;  // 4 fp32 acc
typedef __attribute__((ext_vector_type(4))) uint32_t u32x4;

// low short = u0[31:16], high short = u1[31:16]
__device__ __forceinline__ uint32_t pack_hi16(uint32_t u0, uint32_t u1) {
  return __builtin_amdgcn_perm(u1, u0, 0x07060302u);
}

__device__ __forceinline__ float fast_sigmoid(float v) {
  return __builtin_amdgcn_rcpf(1.0f + __expf(-v));
}
__device__ __forceinline__ float fast_tanh(float v) {
  return fmaf(2.0f, __builtin_amdgcn_rcpf(1.0f + __expf(-2.0f * v)), -1.0f);
}

struct Frag2 { frag_ab hi, lo; };

// fp32x8 -> (hi bf16 x8, lo bf16 x8); hi = trunc16(f), lo = trunc16(f - hi)
__device__ __forceinline__ Frag2 split8(float4 a, float4 b) {
  uint32_t u0 = __float_as_uint(a.x), u1 = __float_as_uint(a.y);
  uint32_t u2 = __float_as_uint(a.z), u3 = __float_as_uint(a.w);
  uint32_t u4 = __float_as_uint(b.x), u5 = __float_as_uint(b.y);
  uint32_t u6 = __float_as_uint(b.z), u7 = __float_as_uint(b.w);
  uint32_t r0 = __float_as_uint(a.x - __uint_as_float(u0 & 0xFFFF0000u));
  uint32_t r1 = __float_as_uint(a.y - __uint_as_float(u1 & 0xFFFF0000u));
  uint32_t r2 = __float_as_uint(a.z - __uint_as_float(u2 & 0xFFFF0000u));
  uint32_t r3 = __float_as_uint(a.w - __uint_as_float(u3 & 0xFFFF0000u));
  uint32_t r4 = __float_as_uint(b.x - __uint_as_float(u4 & 0xFFFF0000u));
  uint32_t r5 = __float_as_uint(b.y - __uint_as_float(u5 & 0xFFFF0000u));
  uint32_t r6 = __float_as_uint(b.z - __uint_as_float(u6 & 0xFFFF0000u));
  uint32_t r7 = __float_as_uint(b.w - __uint_as_float(u7 & 0xFFFF0000u));
  union { u32x4 v; frag_ab f; } H, L;
  H.v[0] = pack_hi16(u0, u1); H.v[1] = pack_hi16(u2, u3);
  H.v[2] = pack_hi16(u4, u5); H.v[3] = pack_hi16(u6, u7);
  L.v[0] = pack_hi16(r0, r1); L.v[1] = pack_hi16(r2, r3);
  L.v[2] = pack_hi16(r4, r5); L.v[3] = pack_hi16(r6, r7);
  Frag2 o; o.hi = H.f; o.lo = L.f; return o;
}

// Grid: 256 blocks = q*64 + c (the 4 batch-quarters of a channel differ by 64
// = 0 mod 8 -> same XCD under round-robin: 4x redundant weight reads L2-hit).
// Block: 512 threads = 8 waves; wave w owns output rows i in [4w, 4w+4) x 4
// gates via the frag-row map (g = frag_n&3, i = 4w + (frag_n>>2)), so all 4
// gates of output i land in one lane's acc[0..3] — no gate exchange.
//
// KEY INSIGHT: weights have ZERO intra-block reuse (each element feeds exactly
// one lane), so LDS-staging them is pure overhead. Weights and x stream
// global->VGPR through a 4-deep register ring (prefetch distance 3 steps;
// compiler emits counted vmcnt at use). LDS holds only the h exchange,
// pre-split into bf16 hi/lo planes so the reader's ds_read_b128 IS the MFMA
// fragment. One lgkmcnt-only barrier per step; x-plane MFMAs run pre-barrier.
__global__ void __launch_bounds__(512, 2)
lstm_kernel(const float* __restrict__ x, const float* __restrict__ xOps,
            const float* __restrict__ hOps, float* __restrict__ out) {
  __shared__ short Hhi[2][16][HS];   // [parity][batch n][j], rows 8..15 stay 0
  __shared__ short Hlo[2][16][HS];

  const int tid    = threadIdx.x;
  const int c      = blockIdx.x & 63;
  const int q      = blockIdx.x >> 6;
  const int w      = tid >> 6;
  const int lane   = tid & 63;
  const int frag_n = lane & 15;       // batch col (valid < 8)
  const int quad   = lane >> 4;

  // Per-lane constant offsets (in floats).
  // A-frag supply: row m=frag_n -> weight row (g=frag_n&3, i=4w+(frag_n>>2)),
  // k-slice = quad*8..+8.  B-frag (x): batch=frag_n (clamped), j=quad*8..+8.
  const int g  = frag_n & 3;
  const int iw = 4 * w + (frag_n >> 2);
  const size_t woff = ((size_t)g * T_STEPS * C_CH + c) * 1024
                    + (size_t)iw * 32 + quad * 8;
  const int bcl = (q * 8 + frag_n) & 31;   // clamp pad lanes into valid memory;
                                           // garbage stays in pad cols (never read)
  const size_t xoff = ((size_t)bcl * T_STEPS * C_CH + c) * 32 + quad * 8;

  // Zero h planes (h(0)=0; pad rows stay 0 forever).
  for (int idx = tid; idx < 2 * 16 * HS; idx += 512) {
    ((short*)Hhi)[idx] = 0; ((short*)Hlo)[idx] = 0;
  }
  __syncthreads();

  // ---- register ring: slots hold steps t..t+2 on loop entry ----
  float4 wv[4][6];
#pragma unroll
  for (int s = 0; s < 3; ++s) {
    const float* pw = xOps + (size_t)s * (C_CH * 1024) + woff;
    wv[s][0] = ((const float4*)pw)[0];
    wv[s][1] = ((const float4*)pw)[1];
    const float* ph = hOps + (size_t)s * (C_CH * 1024) + woff;
    wv[s][2] = ((const float4*)ph)[0];
    wv[s][3] = ((const float4*)ph)[1];
    const float* px = x + (size_t)s * (C_CH * 32) + xoff;
    wv[s][4] = ((const float4*)px)[0];
    wv[s][5] = ((const float4*)px)[1];
  }

  const int hrd = quad * 8;        // h-frag read col base
  const int iq  = 4 * w + quad;    // this lane's output dim
  float c_state = 0.0f;

  for (int tb = 0; tb < T_STEPS; tb += 4) {
#pragma unroll
    for (int u = 0; u < 4; ++u) {
      const int t  = tb + u;
      const int cs = u;              // current ring slot (compile-time)
      const int ps = (u + 3) & 3;    // prefetch ring slot (compile-time)

      // ---- split current step's weights/x; x-plane MFMAs (h-independent) ----
      Frag2 A0 = split8(wv[cs][0], wv[cs][1]);   // xOps rows
      Frag2 A1 = split8(wv[cs][2], wv[cs][3]);   // hOps rows
      Frag2 BX = split8(wv[cs][4], wv[cs][5]);   // x_t
      frag_cd ax = {0.f, 0.f, 0.f, 0.f};
      ax = __builtin_amdgcn_mfma_f32_16x16x32_bf16(A0.hi, BX.hi, ax, 0, 0, 0);
      ax = __builtin_amdgcn_mfma_f32_16x16x32_bf16(A0.hi, BX.lo, ax, 0, 0, 0);
      ax = __builtin_amdgcn_mfma_f32_16x16x32_bf16(A0.lo, BX.hi, ax, 0, 0, 0);

      // ---- issue prefetch for step t+3 (stays in flight ~3 steps) ----
      if (t + 3 < T_STEPS) {
        const float* pw = xOps + (size_t)(t + 3) * (C_CH * 1024) + woff;
        wv[ps][0] = ((const float4*)pw)[0];
        wv[ps][1] = ((const float4*)pw)[1];
        const float* ph = hOps + (size_t)(t + 3) * (C_CH * 1024) + woff;
        wv[ps][2] = ((const float4*)ph)[0];
        wv[ps][3] = ((const float4*)ph)[1];
        const float* px = x + (size_t)(t + 3) * (C_CH * 32) + xoff;
        wv[ps][4] = ((const float4*)px)[0];
        wv[ps][5] = ((const float4*)px)[1];
      }

      // ---- h exchange barrier: LDS-only drain; global loads stay in flight.
      // Orders: step t-1's h-writes (visibility) and h-reads (WAR on parity).
      asm volatile("s_waitcnt lgkmcnt(0)\n\ts_barrier" ::: "memory");

      // ---- h-plane MFMAs: ds_read_b128 delivers pre-split fragments ----
      const int p = t & 1;
      const frag_ab bh = *(const frag_ab*)&Hhi[p][frag_n][hrd];
      const frag_ab bl = *(const frag_ab*)&Hlo[p][frag_n][hrd];
      frag_cd ah = {0.f, 0.f, 0.f, 0.f};
      ah = __builtin_amdgcn_mfma_f32_16x16x32_bf16(A1.hi, bh, ah, 0, 0, 0);
      ah = __builtin_amdgcn_mfma_f32_16x16x32_bf16(A1.hi, bl, ah, 0, 0, 0);
      ah = __builtin_amdgcn_mfma_f32_16x16x32_bf16(A1.lo, bh, ah, 0, 0, 0);

      // ---- cell update in-register: row r of acc = gate r for (i=iq, b=frag_n)
      const float ig = fast_sigmoid(ax[0] + ah[0]);
      const float fg = fast_sigmoid(ax[1] + ah[1]);
      const float gg = fast_tanh(ax[2] + ah[2]);
      const float og = fast_sigmoid(ax[3] + ah[3]);
      c_state = fg * c_state + ig * gg;
      const float hval = og * fast_tanh(c_state);

      if (t == T_STEPS - 1) {
        if (frag_n < 8)
          out[((size_t)(q * 8 + frag_n) * C_CH + c) * 32 + iq] = hval;
      } else if (frag_n < 8) {
        // producer-side hi/lo split: 2 VALU + 2 ds_write_b16; reader reads frags
        const uint32_t uh = __float_as_uint(hval);
        const float    rh = hval - __uint_as_float(uh & 0xFFFF0000u);
        Hhi[p ^ 1][frag_n][iq] = (short)(uh >> 16);
        Hlo[p ^ 1][frag_n][iq] = (short)(__float_as_uint(rh) >> 16);
      }
    }
  }
}

extern "C" void kernel_launch(void* const* d_in, const int* in_sizes, int n_in,
                              void* d_out, int out_size, void* d_ws, size_t ws_size,
                              hipStream_t stream) {
  const float* x    = (const float*)d_in[0];
  const float* xOps = (const float*)d_in[1];
  const float* hOps = (const float*)d_in[2];
  lstm_kernel<<<dim3(256), dim3(512), 0, stream>>>(x, xOps, hOps, (float*)d_out);
}